// Round 6
// baseline (95.795 us; speedup 1.0000x reference)
//
#include <hip/hip_runtime.h>

// Tropical (max-plus) linear layer:
//   out[b, j] = max_k (x[b,k] + w[j,k]) + bias[j]   if any product > -1e38
//             = -1e38                                otherwise
// x: [4096, 256] f32, w: [256, 256] f32, bias: [256] f32, out: [4096, 256] f32
//
// R6: w from LDS at ds-ratio 0.125 (1 b128 per 48 VALU), x via broadcast
// vector loads (address derived from raw tid>>6 -- NO readfirstlane, so the
// compiler cannot promote to s_load; scalar-path streaming was the R3/R4/R5
// disease). Block = 8 waves = 2 row-groups x split-K 4; 64 KB LDS -> 2
// blocks/CU resident = 4 waves/SIMD. Split-K reduced through re-used LDS.

#define TZERO -1e38f

constexpr int K    = 256;
constexpr int N    = 256;
constexpr int Bdim = 4096;
constexpr int BN   = 64;          // cols per block (= lanes)
constexpr int BM   = 16;          // rows per block
constexpr int RPT  = 8;           // rows per thread
constexpr int NKC  = 4;           // split-K chunks
constexpr int KC   = K / NKC;     // 64 k per chunk
constexpr int NT   = 512;         // (BM/RPT=2 row-groups) x NKC=4 -> 8 waves

__global__ __launch_bounds__(NT, 4)
void tropical_kernel(const float* __restrict__ x, const float* __restrict__ w,
                     const float* __restrict__ bias, float* __restrict__ out)
{
    __shared__ float4 wQ[K / 4][BN];              // 64 KB: wQ[k4][col]
    float* red = reinterpret_cast<float*>(wQ);    // epilogue alias: [NKC][BM][BN]

    const int t    = threadIdx.x;
    const int lane = t & 63;
    const int row0 = blockIdx.x * BM;
    const int col0 = blockIdx.y * BN;

    // ---- stage w once: thread (col = t&63, k8 = t>>6) loads 8 float4 along k.
    //      LDS writes are lane-contiguous b128 (conflict-free).
    {
        const int scol = t & 63;
        const int k8   = t >> 6;
        const float* wp = w + (size_t)(col0 + scol) * K + k8 * 32;
#pragma unroll
        for (int i = 0; i < 8; ++i)
            wQ[k8 * 8 + i][scol] = *reinterpret_cast<const float4*>(wp + i * 4);
    }
    __syncthreads();

    // wave role from RAW tid (divergent to the compiler -> x stays on the
    // vector-load path; all 64 lanes share the address -> 1 txn broadcast)
    const int wid = t >> 6;
    const int rg  = wid & 1;        // row-group (0,1)
    const int kc  = wid >> 1;       // k-chunk (0..3)

    const float* xp = x + (size_t)(row0 + rg * RPT) * K + kc * KC;

    float acc[RPT];
#pragma unroll
    for (int r = 0; r < RPT; ++r) acc[r] = -__builtin_inff();

#pragma unroll
    for (int k4 = 0; k4 < KC / 4; ++k4) {
        const float4 wv = wQ[kc * (KC / 4) + k4][lane];   // b128, conflict-free
#pragma unroll
        for (int r = 0; r < RPT; ++r) {
            const float4 xv =
                *reinterpret_cast<const float4*>(xp + r * K + k4 * 4);
            const float t0 = xv.x + wv.x;
            const float t1 = xv.y + wv.y;
            const float t2 = xv.z + wv.z;
            const float t3 = xv.w + wv.w;
            float m = fmaxf(fmaxf(acc[r], t0), t1);   // v_max3_f32
            m       = fmaxf(fmaxf(m, t2), t3);        // v_max3_f32
            acc[r] = m;
        }
    }

    // ---- split-K reduce through LDS (re-use wQ space)
    __syncthreads();   // everyone done reading wQ
#pragma unroll
    for (int r = 0; r < RPT; ++r)
        red[(kc * BM + rg * RPT + r) * BN + lane] = acc[r];   // 2-way, free
    __syncthreads();

    const float bj = bias[col0 + lane];
#pragma unroll
    for (int i = 0; i < 2; ++i) {
        const int row = wid * 2 + i;   // 8 waves x 2 rows = 16
        float m = red[(0 * BM + row) * BN + lane];
        m = fmaxf(m, red[(1 * BM + row) * BN + lane]);
        m = fmaxf(m, red[(2 * BM + row) * BN + lane]);
        m = fmaxf(m, red[(3 * BM + row) * BN + lane]);
        out[(size_t)(row0 + row) * N + col0 + lane] = (m > TZERO) ? m + bj : TZERO;
    }
}

extern "C" void kernel_launch(void* const* d_in, const int* in_sizes, int n_in,
                              void* d_out, int out_size, void* d_ws, size_t ws_size,
                              hipStream_t stream) {
    const float* x  = (const float*)d_in[0];
    const float* w  = (const float*)d_in[1];
    const float* b  = (const float*)d_in[2];
    float* out      = (float*)d_out;

    dim3 grid(Bdim / BM, N / BN);   // (256, 4) = 1024 blocks, 8 waves each
    tropical_kernel<<<grid, NT, 0, stream>>>(x, w, b, out);
}

// Round 7
// 76.606 us; speedup vs baseline: 1.2505x; 1.2505x over previous
//
#include <hip/hip_runtime.h>

// Tropical (max-plus) linear layer:
//   out[b, j] = max_k (x[b,k] + w[j,k]) + bias[j]   if any product > -1e38
//             = -1e38                                otherwise
// x: [4096, 256] f32, w: [256, 256] f32, bias: [256] f32, out: [4096, 256] f32
//
// R7: lane = ROW. x chunk lives in VGPRs (xv[32], gathered once per wave,
// reused across all 8 j-columns). w[j][k] is wave-uniform -> s_load batches
// into SGPRs, consumed as the scalar operand of v_add_f32 (pure 1.5
// instr/pair-op, no readlane, no DS, no broadcast vmem in the hot loop).
// Split-K x8 across the block's waves; 18.4 KB LDS used only for the final
// reduce. VGPR ~55 -> 8 waves/SIMD (max TLP class); 16384 waves total.

#define TZERO -1e38f

constexpr int K    = 256;
constexpr int N    = 256;
constexpr int Bdim = 4096;
constexpr int ROWS = 64;          // rows per block (= lanes)
constexpr int J    = 8;           // cols per block
constexpr int SK   = 8;           // split-K waves per block
constexpr int KC   = K / SK;      // 32 k per wave
constexpr int NT   = 64 * SK;     // 512 threads

__global__ __launch_bounds__(NT, 8)
void tropical_kernel(const float* __restrict__ x, const float* __restrict__ w,
                     const float* __restrict__ bias, float* __restrict__ out)
{
    __shared__ float red[SK][ROWS][J + 1];   // pad 9 -> 2-way (free); 18.4 KB

    const int t    = threadIdx.x;
    const int lane = t & 63;
    const int kc   = __builtin_amdgcn_readfirstlane(t >> 6);  // uniform split-K id
    const int row0 = blockIdx.x * ROWS;
    const int col0 = blockIdx.y * J;

    // ---- x chunk -> VGPRs: xv[i] = x[row0+lane][kc*KC + i]
    //      8 dwordx4 gathers (64 rows x 2 lines), reused across all J columns
    float xv[KC];
    {
        const float* xp = x + (size_t)(row0 + lane) * K + kc * KC;
#pragma unroll
        for (int i4 = 0; i4 < KC / 4; ++i4) {
            const float4 v = *reinterpret_cast<const float4*>(xp + i4 * 4);
            xv[i4 * 4 + 0] = v.x;
            xv[i4 * 4 + 1] = v.y;
            xv[i4 * 4 + 2] = v.z;
            xv[i4 * 4 + 3] = v.w;
        }
    }

    float acc[J];
#pragma unroll
    for (int j = 0; j < J; ++j) acc[j] = -__builtin_inff();

    // ---- hot loop: w via uniform s_load batches (SGPRs), x from VGPRs.
    //      Only SMEM in flight -> lgkm waits target loads issued one full
    //      j-iteration earlier; stalls decorrelate across 8 waves/SIMD.
    const float* wbase = w + (size_t)col0 * K + kc * KC;
#pragma unroll
    for (int j = 0; j < J; ++j) {
        const float* wp = wbase + (size_t)j * K;   // fully uniform address
        float m = acc[j];
#pragma unroll
        for (int i4 = 0; i4 < KC / 4; ++i4) {
            const float w0 = wp[i4 * 4 + 0];   // s_load -> SGPR
            const float w1 = wp[i4 * 4 + 1];
            const float w2 = wp[i4 * 4 + 2];
            const float w3 = wp[i4 * 4 + 3];
            const float t0 = xv[i4 * 4 + 0] + w0;   // v_add_f32 v, s, v
            const float t1 = xv[i4 * 4 + 1] + w1;
            const float t2 = xv[i4 * 4 + 2] + w2;
            const float t3 = xv[i4 * 4 + 3] + w3;
            m = fmaxf(fmaxf(m, t0), t1);   // v_max3_f32
            m = fmaxf(fmaxf(m, t2), t3);   // v_max3_f32
        }
        acc[j] = m;
    }

    // ---- split-K reduce through LDS (epilogue only)
#pragma unroll
    for (int j = 0; j < J; ++j) red[kc][lane][j] = acc[j];   // 2-way, free
    __syncthreads();

    const int jj = t & (J - 1);     // 0..7
    const int r  = t >> 3;          // 0..63
    float m = red[0][r][jj];
#pragma unroll
    for (int q = 1; q < SK; ++q) m = fmaxf(m, red[q][r][jj]);
    const float bj = bias[col0 + jj];
    out[(size_t)(row0 + r) * N + col0 + jj] = (m > TZERO) ? m + bj : TZERO;
}

extern "C" void kernel_launch(void* const* d_in, const int* in_sizes, int n_in,
                              void* d_out, int out_size, void* d_ws, size_t ws_size,
                              hipStream_t stream) {
    const float* x  = (const float*)d_in[0];
    const float* w  = (const float*)d_in[1];
    const float* b  = (const float*)d_in[2];
    float* out      = (float*)d_out;

    dim3 grid(Bdim / ROWS, N / J);   // (64, 32) = 2048 blocks, 8 waves each
    tropical_kernel<<<grid, NT, 0, stream>>>(x, w, b, out);
}

// Round 8
// 74.341 us; speedup vs baseline: 1.2886x; 1.0305x over previous
//
#include <hip/hip_runtime.h>

// Tropical (max-plus) linear layer:
//   out[b, j] = max_k (x[b,k] + w[j,k]) + bias[j]   if any product > -1e38
//             = -1e38                                otherwise
// x: [4096, 256] f32, w: [256, 256] f32, bias: [256] f32, out: [4096, 256] f32
//
// R8: lane = COL. w[col][k-chunk] lives in VGPRs (wr[32]), delivered by a
// one-time LDS transpose fed with perfectly coalesced global reads (no
// per-lane strided gathers anywhere -- R7's TA-serialization disease).
// x is streamed on the SCALAR path (wave-uniform s_load), consumed as the
// SGPR operand of v_add_f32; hot loop has zero DS / zero vmem / zero
// barriers, so lgkm waits cover only pipelined SMEM (R3's DS-mixing disease
// removed). Split-K x8 across the block's waves; LDS reused for the reduce.

#define TZERO -1e38f

constexpr int K    = 256;
constexpr int N    = 256;
constexpr int Bdim = 4096;
constexpr int BN   = 64;          // cols per block (= lanes)
constexpr int RPB  = 8;           // rows per block
constexpr int SK   = 8;           // split-K waves per block
constexpr int KC   = K / SK;      // 32 k per wave
constexpr int NT   = 64 * SK;     // 512 threads
constexpr int LDW  = 65;          // padded stride in float4 (bank-conflict-free)

__global__ __launch_bounds__(NT, 4)
void tropical_kernel(const float* __restrict__ x, const float* __restrict__ w,
                     const float* __restrict__ bias, float* __restrict__ out)
{
    __shared__ float4 wT[64 * LDW];            // 66.5 KB: addr = k4*65 + col
    float* red = reinterpret_cast<float*>(wT); // epilogue alias [SK][RPB][BN]

    const int t    = threadIdx.x;
    const int lane = t & 63;
    const int kc   = __builtin_amdgcn_readfirstlane(t >> 6);  // split-K chunk
    const int row0 = blockIdx.x * RPB;
    const int col0 = blockIdx.y * BN;

    // ---- stage w tile [64 cols][256 k] into LDS, fully coalesced:
    //      iter i: wave reads 1 KB contiguous of one w row (lanes span k4).
    //      LDS write addr = k4*65 + col -> 4-lane/4-bank-group uniform (free).
#pragma unroll
    for (int i = 0; i < (64 * 64) / NT; ++i) {
        const int flat = i * NT + t;
        const int k4   = flat & 63;
        const int col  = flat >> 6;
        wT[k4 * LDW + col] = *reinterpret_cast<const float4*>(
            w + (size_t)(col0 + col) * K + k4 * 4);
    }
    __syncthreads();

    // ---- transpose-read my column's k-chunk into VGPRs (b128, conflict-free)
    float wr[KC];
#pragma unroll
    for (int i4 = 0; i4 < KC / 4; ++i4) {
        const float4 v = wT[(kc * (KC / 4) + i4) * LDW + lane];
        wr[i4 * 4 + 0] = v.x;
        wr[i4 * 4 + 1] = v.y;
        wr[i4 * 4 + 2] = v.z;
        wr[i4 * 4 + 3] = v.w;
    }

    // ---- hot loop: 8 rows; x on the scalar path (wave-uniform addresses),
    //      consumed straight from SGPRs. No DS, no vmem, no barriers.
    const float* xp = x + (size_t)row0 * K + kc * KC;
    float acc[RPB];
#pragma unroll
    for (int r = 0; r < RPB; ++r) {
        const float* xr = xp + r * K;          // wave-uniform
        float m = -__builtin_inff();
#pragma unroll
        for (int i4 = 0; i4 < KC / 4; ++i4) {
            const float x0 = xr[i4 * 4 + 0];   // s_load -> SGPR operand
            const float x1 = xr[i4 * 4 + 1];
            const float x2 = xr[i4 * 4 + 2];
            const float x3 = xr[i4 * 4 + 3];
            const float t0 = x0 + wr[i4 * 4 + 0];   // v_add_f32 v, s, v
            const float t1 = x1 + wr[i4 * 4 + 1];
            const float t2 = x2 + wr[i4 * 4 + 2];
            const float t3 = x3 + wr[i4 * 4 + 3];
            m = fmaxf(fmaxf(m, t0), t1);   // v_max3_f32
            m = fmaxf(fmaxf(m, t2), t3);   // v_max3_f32
        }
        acc[r] = m;
    }

    // ---- split-K reduce through re-used LDS
    __syncthreads();   // all wT reads done
#pragma unroll
    for (int r = 0; r < RPB; ++r)
        red[(kc * RPB + r) * BN + lane] = acc[r];   // lanes span banks, free
    __syncthreads();

    const int r  = t >> 6;          // 0..7
    const int cc = t & 63;          // col
    float m = red[(0 * RPB + r) * BN + cc];
#pragma unroll
    for (int q = 1; q < SK; ++q)
        m = fmaxf(m, red[(q * RPB + r) * BN + cc]);
    const float bj = bias[col0 + cc];
    out[(size_t)(row0 + r) * N + col0 + cc] = (m > TZERO) ? m + bj : TZERO;
}

extern "C" void kernel_launch(void* const* d_in, const int* in_sizes, int n_in,
                              void* d_out, int out_size, void* d_ws, size_t ws_size,
                              hipStream_t stream) {
    const float* x  = (const float*)d_in[0];
    const float* w  = (const float*)d_in[1];
    const float* b  = (const float*)d_in[2];
    float* out      = (float*)d_out;

    dim3 grid(Bdim / RPB, N / BN);   // (512, 4) = 2048 blocks, 8 waves each
    tropical_kernel<<<grid, NT, 0, stream>>>(x, w, b, out);
}